// Round 1
// baseline (2519.105 us; speedup 1.0000x reference)
//
#include <hip/hip_runtime.h>

// Liquid-network scan: one block per batch row (B=128 blocks).
// Thread (j = tid&255, q = tid>>8) holds W_rec[q*128 .. q*128+127][j] in 128 VGPRs.
// h lives in LDS; per step: broadcast-read h as float4, 128 fp32 FMAs/thread,
// cross-half combine, wave-shuffle LN reduce, tanh, Euler update, clip.

#define BB     128
#define TT     2048
#define DIN    16
#define HH     256
#define NAPP   10
#define DT_STEP 0.1f
#define LN_EPS_C 1e-5f

__global__ __launch_bounds__(512, 2)
void liquid_scan_kernel(const float* __restrict__ x,
                        const float* __restrict__ W_in,
                        const float* __restrict__ b_in,
                        const float* __restrict__ tau_param,
                        const float* __restrict__ W_rec,
                        const float* __restrict__ g_intra,
                        const float* __restrict__ b_intra,
                        const float* __restrict__ g_norm,
                        const float* __restrict__ b_norm,
                        const float* __restrict__ W_head,
                        const float* __restrict__ b_head,
                        float* __restrict__ out)
{
    const int tid  = threadIdx.x;
    const int b    = blockIdx.x;
    const int j    = tid & (HH - 1);
    const int q    = tid >> 8;        // 0 or 1 (wave-uniform)
    const int wv   = tid >> 6;        // wave id 0..7
    const int lane = tid & 63;

    __shared__ __align__(16) float h_lds[HH];
    __shared__ float part[HH];
    __shared__ float wred[4][2];
    __shared__ float xbuf[2][DIN];

    // ---- weights into registers (coalesced across j within a wave) ----
    float w[128];
    #pragma unroll
    for (int i = 0; i < 128; ++i)
        w[i] = W_rec[(size_t)(q * 128 + i) * HH + j];

    float win[DIN];
    #pragma unroll
    for (int k = 0; k < DIN; ++k)
        win[k] = W_in[j * DIN + k];

    const float bi   = b_in[j];
    const float gi   = g_intra[j];
    const float bbi  = b_intra[j];
    const float gn   = g_norm[j];
    const float bn   = b_norm[j];
    const float tp   = tau_param[j];
    const float tau  = (tp > 20.f) ? tp : log1pf(__expf(tp));  // softplus
    const float itau = 1.f / tau;

    float hj = 0.f;

    if (tid < HH) h_lds[tid] = 0.f;
    const size_t xbase = (size_t)b * TT * DIN;
    if (tid < DIN) xbuf[0][tid] = x[xbase + tid];
    __syncthreads();

    const int pl = tid - (512 - DIN);   // prefetch lane: last 16 threads (wave 7)

    for (int t = 0; t < TT; ++t) {
        // issue x prefetch for t+1 early; LDS write deferred to late in the step
        float xv = 0.f;
        if (pl >= 0 && t + 1 < TT)
            xv = x[xbase + (size_t)(t + 1) * DIN + pl];

        // ---- partial rec over this thread's 128 rows (4 indep. acc chains) ----
        const float4* h4 = (const float4*)h_lds;
        float a0 = 0.f, a1 = 0.f, a2 = 0.f, a3 = 0.f;
        #pragma unroll
        for (int ii = 0; ii < 32; ++ii) {
            float4 hv = h4[q * 32 + ii];          // broadcast read
            a0 = fmaf(hv.x, w[ii * 4 + 0], a0);
            a1 = fmaf(hv.y, w[ii * 4 + 1], a1);
            a2 = fmaf(hv.z, w[ii * 4 + 2], a2);
            a3 = fmaf(hv.w, w[ii * 4 + 3], a3);
        }
        const float acc = (a0 + a1) + (a2 + a3);

        float uin = 0.f;
        if (q == 0) {
            uin = bi;
            #pragma unroll
            for (int k = 0; k < DIN; ++k)
                uin = fmaf(xbuf[t & 1][k], win[k], uin);
        } else {
            part[j] = acc;
        }
        __syncthreads();   // A: partials visible; all h reads done

        float u = 0.f;
        if (q == 0) {
            u = uin + acc + part[j];
            float s1 = u, s2 = u * u;
            #pragma unroll
            for (int off = 32; off >= 1; off >>= 1) {
                s1 += __shfl_xor(s1, off);
                s2 += __shfl_xor(s2, off);
            }
            if (lane == 0) { wred[wv][0] = s1; wred[wv][1] = s2; }
        }
        __syncthreads();   // B: wave partials visible

        if (q == 0) {
            const float S1 = (wred[0][0] + wred[1][0]) + (wred[2][0] + wred[3][0]);
            const float S2 = (wred[0][1] + wred[1][1]) + (wred[2][1] + wred[3][1]);
            const float mu  = S1 * (1.f / HH);
            const float var = S2 * (1.f / HH) - mu * mu;
            const float rs  = rsqrtf(var + LN_EPS_C);
            const float xn  = (u - mu) * rs * gi + bbi;
            // tanh(x) = 1 - 2/(exp(2x)+1); saturates correctly via inf/0
            const float e = __expf(2.f * xn);
            const float f = 1.f - 2.f / (e + 1.f);
            float hn = hj + (f - hj * itau) * DT_STEP;
            hn = fminf(10.f, fmaxf(-10.f, hn));
            hj = hn;
            h_lds[j] = hn;
        } else if (pl >= 0 && t + 1 < TT) {
            xbuf[(t + 1) & 1][pl] = xv;   // vmcnt wait lands here, hidden under LN
        }
        __syncthreads();   // C: new h + next x visible
    }

    // ---- final LayerNorm (g_norm, b_norm) + head ----
    if (q == 0) {
        float s1 = hj, s2 = hj * hj;
        #pragma unroll
        for (int off = 32; off >= 1; off >>= 1) {
            s1 += __shfl_xor(s1, off);
            s2 += __shfl_xor(s2, off);
        }
        if (lane == 0) { wred[wv][0] = s1; wred[wv][1] = s2; }
    }
    __syncthreads();
    if (q == 0) {
        const float S1 = (wred[0][0] + wred[1][0]) + (wred[2][0] + wred[3][0]);
        const float S2 = (wred[0][1] + wred[1][1]) + (wred[2][1] + wred[3][1]);
        const float mu  = S1 * (1.f / HH);
        const float var = S2 * (1.f / HH) - mu * mu;
        const float rs  = rsqrtf(var + LN_EPS_C);
        part[j] = (hj - mu) * rs * gn + bn;
    }
    __syncthreads();
    if (tid < NAPP) {
        float o = b_head[tid];
        for (int jj = 0; jj < HH; ++jj)
            o = fmaf(part[jj], W_head[jj * NAPP + tid], o);
        out[(size_t)b * NAPP + tid] = o;
    }
}

extern "C" void kernel_launch(void* const* d_in, const int* in_sizes, int n_in,
                              void* d_out, int out_size, void* d_ws, size_t ws_size,
                              hipStream_t stream) {
    const float* x       = (const float*)d_in[0];
    const float* W_in    = (const float*)d_in[1];
    const float* b_in    = (const float*)d_in[2];
    const float* tau     = (const float*)d_in[3];
    const float* W_rec   = (const float*)d_in[4];
    const float* g_intra = (const float*)d_in[5];
    const float* b_intra = (const float*)d_in[6];
    const float* g_norm  = (const float*)d_in[7];
    const float* b_norm  = (const float*)d_in[8];
    const float* W_head  = (const float*)d_in[9];
    const float* b_head  = (const float*)d_in[10];
    float* out = (float*)d_out;

    hipLaunchKernelGGL(liquid_scan_kernel, dim3(BB), dim3(512), 0, stream,
                       x, W_in, b_in, tau, W_rec, g_intra, b_intra,
                       g_norm, b_norm, W_head, b_head, out);
}

// Round 2
// 2280.483 us; speedup vs baseline: 1.1046x; 1.1046x over previous
//
#include <hip/hip_runtime.h>

// Liquid-network scan: one block per batch row (B=128 blocks), 512 threads.
// Thread (j = tid&255, q = tid>>8) owns output column j, k-range [q*128, q*128+128).
// h is delivered via the SGPR broadcast port: each lane holds one packed-fp16
// h-pair; inner loop = v_readlane (per-wave SGPR broadcast) + v_dot2_f32_f16.
// This replaces the LDS-broadcast path (256 ds_read_b128/CU/step ~ 2950 cyc)
// with ~128 VALU instrs/wave/step.

#define BB     128
#define TT     2048
#define DIN    16
#define HH     256
#define NAPP   10
#define DT_STEP 0.1f
#define LN_EPS_C 1e-5f

typedef _Float16 half2_t __attribute__((ext_vector_type(2)));

__global__ __launch_bounds__(512, 2)
void liquid_scan_kernel(const float* __restrict__ x,
                        const float* __restrict__ W_in,
                        const float* __restrict__ b_in,
                        const float* __restrict__ tau_param,
                        const float* __restrict__ W_rec,
                        const float* __restrict__ g_intra,
                        const float* __restrict__ b_intra,
                        const float* __restrict__ g_norm,
                        const float* __restrict__ b_norm,
                        const float* __restrict__ W_head,
                        const float* __restrict__ b_head,
                        float* __restrict__ out)
{
    const int tid  = threadIdx.x;
    const int b    = blockIdx.x;
    const int j    = tid & (HH - 1);
    const int q    = tid >> 8;        // 0 or 1 (wave-uniform)
    const int wv   = tid >> 6;        // wave id 0..7
    const int lane = tid & 63;

    __shared__ __align__(16) float h_lds[HH];
    __shared__ float part[HH];
    __shared__ float wred[4][2];
    __shared__ __align__(16) float xbuf[2][DIN];

    // ---- packed recurrent weights (RNE at init): w2[kk] = (W[k][j], W[k+1][j]), k = q*128+2kk
    half2_t w2[64];
    #pragma unroll
    for (int kk = 0; kk < 64; ++kk) {
        const float wa = W_rec[(size_t)(q * 128 + 2 * kk) * HH + j];
        const float wb = W_rec[(size_t)(q * 128 + 2 * kk + 1) * HH + j];
        half2_t t2; t2.x = (_Float16)wa; t2.y = (_Float16)wb;
        w2[kk] = t2;
    }

    float win[DIN];
    #pragma unroll
    for (int k = 0; k < DIN; ++k)
        win[k] = W_in[j * DIN + k];

    const float bi   = b_in[j];
    const float gi   = g_intra[j];
    const float bbi  = b_intra[j];
    const float gn   = g_norm[j];
    const float bn   = b_norm[j];
    const float tp   = tau_param[j];
    const float tau  = (tp > 20.f) ? tp : log1pf(__expf(tp));  // softplus
    const float itau = 1.f / tau;

    float hj  = 0.f;
    int   hpk = 0;                    // packed fp16 pair (h[q*128+2*lane], h[+1]) = (0,0)

    if (tid < HH) h_lds[tid] = 0.f;
    const size_t xbase = (size_t)b * TT * DIN;
    if (tid < DIN) xbuf[0][tid] = x[xbase + tid];
    __syncthreads();

    const int pl = tid - (512 - DIN);   // prefetch lanes: last 16 threads (wave 7, q=1)

    for (int t = 0; t < TT; ++t) {
        // issue x prefetch for t+1 early; LDS write deferred to late in the step
        float xv = 0.f;
        if (pl >= 0 && t + 1 < TT)
            xv = x[xbase + (size_t)(t + 1) * DIN + pl];

        // ---- rec partial: 64 (readlane -> SGPR broadcast) + 64 dot2, 4 indep chains
        float a0 = 0.f, a1 = 0.f, a2 = 0.f, a3 = 0.f;
        #pragma unroll
        for (int kk = 0; kk < 64; kk += 4) {
            int s0 = __builtin_amdgcn_readlane(hpk, kk + 0);
            int s1i = __builtin_amdgcn_readlane(hpk, kk + 1);
            int s2i = __builtin_amdgcn_readlane(hpk, kk + 2);
            int s3i = __builtin_amdgcn_readlane(hpk, kk + 3);
            a0 = __builtin_amdgcn_fdot2(__builtin_bit_cast(half2_t, s0),  w2[kk + 0], a0, false);
            a1 = __builtin_amdgcn_fdot2(__builtin_bit_cast(half2_t, s1i), w2[kk + 1], a1, false);
            a2 = __builtin_amdgcn_fdot2(__builtin_bit_cast(half2_t, s2i), w2[kk + 2], a2, false);
            a3 = __builtin_amdgcn_fdot2(__builtin_bit_cast(half2_t, s3i), w2[kk + 3], a3, false);
        }
        const float acc = (a0 + a1) + (a2 + a3);

        float uin = 0.f;
        if (q == 0) {
            uin = bi;
            #pragma unroll
            for (int k = 0; k < DIN; ++k)
                uin = fmaf(xbuf[t & 1][k], win[k], uin);
        } else {
            part[j] = acc;
        }
        __syncthreads();   // A: q=1 partials visible

        float u = 0.f;
        if (q == 0) {
            u = uin + acc + part[j];
            float s1 = u, s2 = u * u;
            #pragma unroll
            for (int off = 32; off >= 1; off >>= 1) {
                s1 += __shfl_xor(s1, off);
                s2 += __shfl_xor(s2, off);
            }
            if (lane == 0) { wred[wv][0] = s1; wred[wv][1] = s2; }
        }
        __syncthreads();   // B: wave partials visible

        if (q == 0) {
            const float S1 = (wred[0][0] + wred[1][0]) + (wred[2][0] + wred[3][0]);
            const float S2 = (wred[0][1] + wred[1][1]) + (wred[2][1] + wred[3][1]);
            const float mu  = S1 * (1.f / HH);
            const float var = S2 * (1.f / HH) - mu * mu;
            const float rs  = rsqrtf(var + LN_EPS_C);
            const float xn  = (u - mu) * rs * gi + bbi;
            // tanh(x) = 1 - 2/(exp(2x)+1); saturates correctly via inf/0
            const float e = __expf(2.f * xn);
            const float f = 1.f - 2.f / (e + 1.f);
            float hn = hj + (f - hj * itau) * DT_STEP;
            hn = fminf(10.f, fmaxf(-10.f, hn));
            hj = hn;
            h_lds[j] = hn;
        } else if (pl >= 0 && t + 1 < TT) {
            xbuf[(t + 1) & 1][pl] = xv;   // vmcnt wait lands here, hidden under LN
        }
        __syncthreads();   // C: new h + next x visible

        // ---- repack own h-pair for next step: lane holds (h[q*128+2l], h[q*128+2l+1])
        {
            const float2* hp2 = (const float2*)h_lds;
            const float2 hv = hp2[q * 64 + lane];
            hpk = __builtin_bit_cast(int, __builtin_amdgcn_cvt_pkrtz(hv.x, hv.y));
        }
    }

    // ---- final LayerNorm (g_norm, b_norm) + head ----
    if (q == 0) {
        float s1 = hj, s2 = hj * hj;
        #pragma unroll
        for (int off = 32; off >= 1; off >>= 1) {
            s1 += __shfl_xor(s1, off);
            s2 += __shfl_xor(s2, off);
        }
        if (lane == 0) { wred[wv][0] = s1; wred[wv][1] = s2; }
    }
    __syncthreads();
    if (q == 0) {
        const float S1 = (wred[0][0] + wred[1][0]) + (wred[2][0] + wred[3][0]);
        const float S2 = (wred[0][1] + wred[1][1]) + (wred[2][1] + wred[3][1]);
        const float mu  = S1 * (1.f / HH);
        const float var = S2 * (1.f / HH) - mu * mu;
        const float rs  = rsqrtf(var + LN_EPS_C);
        part[j] = (hj - mu) * rs * gn + bn;
    }
    __syncthreads();
    if (tid < NAPP) {
        float o = b_head[tid];
        for (int jj = 0; jj < HH; ++jj)
            o = fmaf(part[jj], W_head[jj * NAPP + tid], o);
        out[(size_t)b * NAPP + tid] = o;
    }
}

extern "C" void kernel_launch(void* const* d_in, const int* in_sizes, int n_in,
                              void* d_out, int out_size, void* d_ws, size_t ws_size,
                              hipStream_t stream) {
    const float* x       = (const float*)d_in[0];
    const float* W_in    = (const float*)d_in[1];
    const float* b_in    = (const float*)d_in[2];
    const float* tau     = (const float*)d_in[3];
    const float* W_rec   = (const float*)d_in[4];
    const float* g_intra = (const float*)d_in[5];
    const float* b_intra = (const float*)d_in[6];
    const float* g_norm  = (const float*)d_in[7];
    const float* b_norm  = (const float*)d_in[8];
    const float* W_head  = (const float*)d_in[9];
    const float* b_head  = (const float*)d_in[10];
    float* out = (float*)d_out;

    hipLaunchKernelGGL(liquid_scan_kernel, dim3(BB), dim3(512), 0, stream,
                       x, W_in, b_in, tau, W_rec, g_intra, b_intra,
                       g_norm, b_norm, W_head, b_head, out);
}

// Round 3
// 1872.230 us; speedup vs baseline: 1.3455x; 1.2181x over previous
//
#include <hip/hip_runtime.h>

// Liquid-network scan: one block per batch row (B=128 blocks), 256 threads.
// Thread j owns output column j with the FULL K=256 dot (no k-split -> no
// partial-combine barrier). h is broadcast via v_readlane of packed-fp16
// pairs (2 regs/lane); LN reduce is pure-VALU DPP (row_shr + row_bcast),
// killing the 6-level ds_swizzle chain (~650 cyc) from the previous version.
// 2 barriers/step: [B] cross-wave LN partials, [C] new h + next-x visible.

#define BB     128
#define TT     2048
#define DIN    16
#define HH     256
#define NAPP   10
#define DT_STEP 0.1f
#define LN_EPS_C 1e-5f

typedef _Float16 half2_t __attribute__((ext_vector_type(2)));

template<int CTRL>
__device__ __forceinline__ float dpp_mov0(float x) {
    // update_dpp(old=0, src, ctrl, row_mask=0xF, bank_mask=0xF, bound_ctrl=true)
    return __builtin_bit_cast(float,
        __builtin_amdgcn_update_dpp(0, __builtin_bit_cast(int, x), CTRL, 0xF, 0xF, true));
}

// After this, lane 63 holds the wave-wide sums of s1 and s2.
__device__ __forceinline__ void wave_reduce2(float& s1, float& s2) {
    s1 += dpp_mov0<0x111>(s1); s2 += dpp_mov0<0x111>(s2);  // row_shr:1
    s1 += dpp_mov0<0x112>(s1); s2 += dpp_mov0<0x112>(s2);  // row_shr:2
    s1 += dpp_mov0<0x114>(s1); s2 += dpp_mov0<0x114>(s2);  // row_shr:4
    s1 += dpp_mov0<0x118>(s1); s2 += dpp_mov0<0x118>(s2);  // row_shr:8
    s1 += dpp_mov0<0x142>(s1); s2 += dpp_mov0<0x142>(s2);  // row_bcast:15
    s1 += dpp_mov0<0x143>(s1); s2 += dpp_mov0<0x143>(s2);  // row_bcast:31
}

__device__ __forceinline__ half2_t as_h2(int v) { return __builtin_bit_cast(half2_t, v); }

__global__ __launch_bounds__(256, 1)
void liquid_scan_kernel(const float* __restrict__ x,
                        const float* __restrict__ W_in,
                        const float* __restrict__ b_in,
                        const float* __restrict__ tau_param,
                        const float* __restrict__ W_rec,
                        const float* __restrict__ g_intra,
                        const float* __restrict__ b_intra,
                        const float* __restrict__ g_norm,
                        const float* __restrict__ b_norm,
                        const float* __restrict__ W_head,
                        const float* __restrict__ b_head,
                        float* __restrict__ out)
{
    const int tid  = threadIdx.x;
    const int b    = blockIdx.x;
    const int j    = tid;             // 0..255
    const int wv   = tid >> 6;        // wave id 0..3
    const int lane = tid & 63;

    __shared__ __align__(16) float h_lds[HH];
    __shared__ __align__(16) float wred[4][2];
    __shared__ __align__(16) float xbuf[2][DIN];
    __shared__ float part[HH];

    // ---- packed recurrent weights (RNE at init): w2[p] = (W[2p][j], W[2p+1][j])
    half2_t w2[128];
    #pragma unroll
    for (int p = 0; p < 128; ++p) {
        const float wa = W_rec[(size_t)(2 * p)     * HH + j];
        const float wb = W_rec[(size_t)(2 * p + 1) * HH + j];
        half2_t t2; t2.x = (_Float16)wa; t2.y = (_Float16)wb;
        w2[p] = t2;
    }

    float win[DIN];
    #pragma unroll
    for (int k = 0; k < DIN; ++k)
        win[k] = W_in[j * DIN + k];

    const float bi   = b_in[j];
    const float gi   = g_intra[j];
    const float bbi  = b_intra[j];
    const float gn   = g_norm[j];
    const float bn   = b_norm[j];
    const float tp   = tau_param[j];
    const float tau  = (tp > 20.f) ? tp : log1pf(__expf(tp));  // softplus
    const float itau = 1.f / tau;

    float hj   = 0.f;
    int   hpk0 = 0;   // packed fp16 pair (h[2*lane],    h[2*lane+1])
    int   hpk1 = 0;   // packed fp16 pair (h[128+2*lane], h[128+2*lane+1])

    const size_t xbase = (size_t)b * TT * DIN;
    if (tid < DIN) xbuf[0][tid] = x[xbase + tid];
    __syncthreads();

    const int pl = tid - (256 - DIN);   // prefetch lanes: last 16 threads (wave 3)

    for (int t = 0; t < TT; ++t) {
        // issue x prefetch for t+1 early; LDS write deferred to late in the step
        float xv = 0.f;
        if (pl >= 0 && t + 1 < TT)
            xv = x[xbase + (size_t)(t + 1) * DIN + pl];

        // ---- full-K dot: 128 (readlane -> SGPR broadcast) + 128 dot2, 4 chains
        float a0 = 0.f, a1 = 0.f, a2 = 0.f, a3 = 0.f;
        #pragma unroll
        for (int p = 0; p < 64; p += 4) {
            const int s0 = __builtin_amdgcn_readlane(hpk0, p + 0);
            const int s1i = __builtin_amdgcn_readlane(hpk0, p + 1);
            const int s2i = __builtin_amdgcn_readlane(hpk0, p + 2);
            const int s3i = __builtin_amdgcn_readlane(hpk0, p + 3);
            a0 = __builtin_amdgcn_fdot2(as_h2(s0),  w2[p + 0], a0, false);
            a1 = __builtin_amdgcn_fdot2(as_h2(s1i), w2[p + 1], a1, false);
            a2 = __builtin_amdgcn_fdot2(as_h2(s2i), w2[p + 2], a2, false);
            a3 = __builtin_amdgcn_fdot2(as_h2(s3i), w2[p + 3], a3, false);
        }
        #pragma unroll
        for (int p = 0; p < 64; p += 4) {
            const int s0 = __builtin_amdgcn_readlane(hpk1, p + 0);
            const int s1i = __builtin_amdgcn_readlane(hpk1, p + 1);
            const int s2i = __builtin_amdgcn_readlane(hpk1, p + 2);
            const int s3i = __builtin_amdgcn_readlane(hpk1, p + 3);
            a0 = __builtin_amdgcn_fdot2(as_h2(s0),  w2[64 + p + 0], a0, false);
            a1 = __builtin_amdgcn_fdot2(as_h2(s1i), w2[64 + p + 1], a1, false);
            a2 = __builtin_amdgcn_fdot2(as_h2(s2i), w2[64 + p + 2], a2, false);
            a3 = __builtin_amdgcn_fdot2(as_h2(s3i), w2[64 + p + 3], a3, false);
        }
        const float acc = (a0 + a1) + (a2 + a3);

        // ---- input projection (broadcast reads of 64B xbuf)
        float uin = bi;
        {
            const float4* xb = (const float4*)xbuf[t & 1];
            const float4 x0 = xb[0], x1 = xb[1], x2 = xb[2], x3 = xb[3];
            uin = fmaf(x0.x, win[0],  uin); uin = fmaf(x0.y, win[1],  uin);
            uin = fmaf(x0.z, win[2],  uin); uin = fmaf(x0.w, win[3],  uin);
            uin = fmaf(x1.x, win[4],  uin); uin = fmaf(x1.y, win[5],  uin);
            uin = fmaf(x1.z, win[6],  uin); uin = fmaf(x1.w, win[7],  uin);
            uin = fmaf(x2.x, win[8],  uin); uin = fmaf(x2.y, win[9],  uin);
            uin = fmaf(x2.z, win[10], uin); uin = fmaf(x2.w, win[11], uin);
            uin = fmaf(x3.x, win[12], uin); uin = fmaf(x3.y, win[13], uin);
            uin = fmaf(x3.z, win[14], uin); uin = fmaf(x3.w, win[15], uin);
        }

        const float u = uin + acc;

        // ---- LN reduce: pure-VALU DPP within wave, LDS only across 4 waves
        float s1 = u, s2 = u * u;
        wave_reduce2(s1, s2);
        if (lane == 63) { wred[wv][0] = s1; wred[wv][1] = s2; }
        __syncthreads();   // B

        const float4 ra = ((const float4*)wred)[0];
        const float4 rb = ((const float4*)wred)[1];
        const float S1 = (ra.x + ra.z) + (rb.x + rb.z);
        const float S2 = (ra.y + ra.w) + (rb.y + rb.w);
        const float mu  = S1 * (1.f / HH);
        const float var = S2 * (1.f / HH) - mu * mu;
        const float rs  = rsqrtf(var + LN_EPS_C);
        const float xn  = (u - mu) * rs * gi + bbi;
        // tanh(x) = 1 - 2/(exp(2x)+1); saturates correctly via inf/0
        const float e = __expf(2.f * xn);
        const float f = 1.f - 2.f / (e + 1.f);
        float hn = hj + (f - hj * itau) * DT_STEP;
        hn = fminf(10.f, fmaxf(-10.f, hn));
        hj = hn;
        h_lds[j] = hn;
        if (pl >= 0 && t + 1 < TT)
            xbuf[(t + 1) & 1][pl] = xv;   // vmcnt wait hidden under the whole step
        __syncthreads();   // C

        // ---- repack broadcast source pairs for next step
        {
            const float2* hp2 = (const float2*)h_lds;
            const float2 h0 = hp2[lane];
            const float2 h1 = hp2[lane + 64];
            hpk0 = __builtin_bit_cast(int, __builtin_amdgcn_cvt_pkrtz(h0.x, h0.y));
            hpk1 = __builtin_bit_cast(int, __builtin_amdgcn_cvt_pkrtz(h1.x, h1.y));
        }
    }

    // ---- final LayerNorm (g_norm, b_norm) + head ----
    {
        float s1 = hj, s2 = hj * hj;
        wave_reduce2(s1, s2);
        if (lane == 63) { wred[wv][0] = s1; wred[wv][1] = s2; }
    }
    __syncthreads();
    {
        const float4 ra = ((const float4*)wred)[0];
        const float4 rb = ((const float4*)wred)[1];
        const float S1 = (ra.x + ra.z) + (rb.x + rb.z);
        const float S2 = (ra.y + ra.w) + (rb.y + rb.w);
        const float mu  = S1 * (1.f / HH);
        const float var = S2 * (1.f / HH) - mu * mu;
        const float rs  = rsqrtf(var + LN_EPS_C);
        part[j] = (hj - mu) * rs * gn + bn;
    }
    __syncthreads();
    if (tid < NAPP) {
        float o = b_head[tid];
        for (int jj = 0; jj < HH; ++jj)
            o = fmaf(part[jj], W_head[jj * NAPP + tid], o);
        out[(size_t)b * NAPP + tid] = o;
    }
}

extern "C" void kernel_launch(void* const* d_in, const int* in_sizes, int n_in,
                              void* d_out, int out_size, void* d_ws, size_t ws_size,
                              hipStream_t stream) {
    const float* x       = (const float*)d_in[0];
    const float* W_in    = (const float*)d_in[1];
    const float* b_in    = (const float*)d_in[2];
    const float* tau     = (const float*)d_in[3];
    const float* W_rec   = (const float*)d_in[4];
    const float* g_intra = (const float*)d_in[5];
    const float* b_intra = (const float*)d_in[6];
    const float* g_norm  = (const float*)d_in[7];
    const float* b_norm  = (const float*)d_in[8];
    const float* W_head  = (const float*)d_in[9];
    const float* b_head  = (const float*)d_in[10];
    float* out = (float*)d_out;

    hipLaunchKernelGGL(liquid_scan_kernel, dim3(BB), dim3(256), 0, stream,
                       x, W_in, b_in, tau, W_rec, g_intra, b_intra,
                       g_norm, b_norm, W_head, b_head, out);
}